// Round 1
// baseline (1766.754 us; speedup 1.0000x reference)
//
#include <hip/hip_runtime.h>

#define F 128

__global__ __launch_bounds__(256)
void deg_kernel(const int* __restrict__ src, const int* __restrict__ dst,
                float* __restrict__ deg_out, float* __restrict__ deg_in, int E) {
    int e = blockIdx.x * blockDim.x + threadIdx.x;
    if (e < E) {
        atomicAdd(&deg_out[src[e]], 1.0f);
        atomicAdd(&deg_in[dst[e]], 1.0f);
    }
}

// 32 threads per edge; each thread handles 4 contiguous feats (float4).
__global__ __launch_bounds__(256)
void scatter_kernel(const float* __restrict__ x, const int* __restrict__ src,
                    const int* __restrict__ dst, const float* __restrict__ deg_out,
                    float* __restrict__ h, int E) {
    long long tid = (long long)blockIdx.x * blockDim.x + threadIdx.x;
    int e = (int)(tid >> 5);
    int q = (int)(tid & 31);
    if (e >= E) return;
    int s = src[e];
    int d = dst[e];
    float invs = rsqrtf(fmaxf(deg_out[s], 1.0f));
    const float4 v = ((const float4*)(x + (long long)s * F))[q];
    float* hp = h + (long long)d * F + q * 4;
    atomicAdd(hp + 0, v.x * invs);
    atomicAdd(hp + 1, v.y * invs);
    atomicAdd(hp + 2, v.z * invs);
    atomicAdd(hp + 3, v.w * invs);
}

// One block = 128 threads = 128 output feats. W cached in LDS (64 KB).
// Grid-stride over rows. h[r][k] is wave-uniform -> broadcast load (L1).
__global__ __launch_bounds__(128)
void gemm_kernel(const float* __restrict__ h, const float* __restrict__ W,
                 const float* __restrict__ bias, const float* __restrict__ deg_in,
                 float* __restrict__ out, int N) {
    __shared__ float Ws[F * F];   // exactly 64 KB
    int t = threadIdx.x;
    for (int i = t; i < F * F; i += 128) Ws[i] = W[i];
    __syncthreads();
    float b = bias[t];
    for (int r = blockIdx.x; r < N; r += gridDim.x) {
        const float* hrow = h + (long long)r * F;
        float acc = 0.0f;
        #pragma unroll 8
        for (int k = 0; k < F; ++k) {
            acc += hrow[k] * Ws[k * F + t];
        }
        float invd = rsqrtf(fmaxf(deg_in[r], 1.0f));
        out[(long long)r * F + t] = acc * invd + b;
    }
}

extern "C" void kernel_launch(void* const* d_in, const int* in_sizes, int n_in,
                              void* d_out, int out_size, void* d_ws, size_t ws_size,
                              hipStream_t stream) {
    const float* x    = (const float*)d_in[0];
    const int*   src  = (const int*)d_in[1];
    const int*   dst  = (const int*)d_in[2];
    const float* W    = (const float*)d_in[3];
    const float* bias = (const float*)d_in[4];
    float* out = (float*)d_out;

    const int N = in_sizes[0] / F;     // 50000
    const int E = in_sizes[1];         // 800000

    float* deg_out = (float*)d_ws;     // [N]
    float* deg_in  = deg_out + N;      // [N]
    float* h       = deg_in + N;       // [N*F]

    size_t zero_bytes = ((size_t)2 * N + (size_t)N * F) * sizeof(float);
    hipMemsetAsync(d_ws, 0, zero_bytes, stream);

    // degrees
    deg_kernel<<<(E + 255) / 256, 256, 0, stream>>>(src, dst, deg_out, deg_in, E);

    // scatter-add aggregation: E * 32 threads
    long long sc_threads = (long long)E * 32;
    int sc_blocks = (int)((sc_threads + 255) / 256);
    scatter_kernel<<<sc_blocks, 256, 0, stream>>>(x, src, dst, deg_out, h, E);

    // GEMM + right-norm + bias
    gemm_kernel<<<4096, 128, 0, stream>>>(h, W, bias, deg_in, out, N);
}

// Round 2
// 414.321 us; speedup vs baseline: 4.2642x; 4.2642x over previous
//
#include <hip/hip_runtime.h>

#define F 128

// ---- 1. degree counts (int atomics) ----
__global__ __launch_bounds__(256)
void deg_kernel(const int* __restrict__ src, const int* __restrict__ dst,
                int* __restrict__ cnt_out, int* __restrict__ cnt_in, int E) {
    int e = blockIdx.x * blockDim.x + threadIdx.x;
    if (e < E) {
        atomicAdd(&cnt_out[src[e]], 1);
        atomicAdd(&cnt_in[dst[e]], 1);
    }
}

// ---- 2. single-block exclusive scan of cnt_in -> row_off; cursor copy into cnt_in ----
__global__ __launch_bounds__(1024)
void scan_kernel(int* __restrict__ cnt_in, int* __restrict__ row_off, int N) {
    __shared__ int part[1024];
    const int t = threadIdx.x;
    const int C = (N + 1023) / 1024;           // chunk per thread
    const int lo = t * C;
    const int hi = min(lo + C, N);
    int s = 0;
    for (int i = lo; i < hi; ++i) s += cnt_in[i];
    part[t] = s;
    __syncthreads();
    // Hillis-Steele inclusive scan
    for (int off = 1; off < 1024; off <<= 1) {
        int v = (t >= off) ? part[t - off] : 0;
        __syncthreads();
        part[t] += v;
        __syncthreads();
    }
    int base = part[t] - s;                    // exclusive prefix
    for (int i = lo; i < hi; ++i) {
        int c = cnt_in[i];
        row_off[i] = base;
        cnt_in[i] = base;                      // cursor init
        base += c;
    }
    if (t == 1023) row_off[N] = part[1023];
}

// ---- 3. inv_out = rsqrt(max(deg_out,1)) ----
__global__ __launch_bounds__(256)
void inv_kernel(const int* __restrict__ cnt_out, float* __restrict__ inv_out, int N) {
    int i = blockIdx.x * blockDim.x + threadIdx.x;
    if (i < N) inv_out[i] = rsqrtf(fmaxf((float)cnt_out[i], 1.0f));
}

// ---- 4. bucket edges into CSR (cursor = cnt_in buffer) ----
__global__ __launch_bounds__(256)
void fill_kernel(const int* __restrict__ src, const int* __restrict__ dst,
                 int* __restrict__ cursor, int* __restrict__ csr_src, int E) {
    int e = blockIdx.x * blockDim.x + threadIdx.x;
    if (e < E) {
        int pos = atomicAdd(&cursor[dst[e]], 1);
        csr_src[pos] = src[e];
    }
}

// ---- 5. gather: one wave per node, 64 lanes x float2 = 128 feats ----
// h[v] = rsqrt(max(deg_in,1)) * sum_{u in N_in(v)} x[u] * inv_out[u]
__global__ __launch_bounds__(256)
void gather_kernel(const float* __restrict__ x, const int* __restrict__ csr_src,
                   const int* __restrict__ row_off, const float* __restrict__ inv_out,
                   float* __restrict__ h, int N) {
    int v = blockIdx.x * 4 + (threadIdx.x >> 6);
    if (v >= N) return;
    int lane = threadIdx.x & 63;
    int beg = row_off[v];
    int end = row_off[v + 1];
    float2 acc = make_float2(0.0f, 0.0f);
    for (int j = beg; j < end; ++j) {
        int s = csr_src[j];                               // wave-broadcast
        float is = inv_out[s];                            // wave-broadcast
        float2 xv = *(const float2*)(x + (long long)s * F + lane * 2);
        acc.x = fmaf(xv.x, is, acc.x);
        acc.y = fmaf(xv.y, is, acc.y);
    }
    float invd = rsqrtf(fmaxf((float)(end - beg), 1.0f));
    ((float2*)(h + (long long)v * F))[lane] = make_float2(acc.x * invd, acc.y * invd);
}

// ---- 6. tiled GEMM: out = h @ W + bias. 32 rows x 128 cols per block ----
__global__ __launch_bounds__(256)
void gemm_kernel(const float* __restrict__ h, const float* __restrict__ W,
                 const float* __restrict__ bias, float* __restrict__ out, int N) {
    __shared__ float Ws[32 * 128];        // [kk][c]       16 KB
    __shared__ float Hs[32 * 36];         // [kk][r] pad36  4.6 KB
    const int t = threadIdx.x;
    const int r0 = blockIdx.x * 32;
    const int tc = t & 31;                // col group: cols 4tc..4tc+3
    const int tr = t >> 5;                // row group: rows 4tr..4tr+3

    float4 a0 = {0,0,0,0}, a1 = {0,0,0,0}, a2 = {0,0,0,0}, a3 = {0,0,0,0};

    for (int kc = 0; kc < 4; ++kc) {
        const int k0 = kc * 32;
        // stage W chunk: 32x128 floats, coalesced
        #pragma unroll
        for (int j = 0; j < 16; ++j) {
            int i = t + 256 * j;          // 0..4095
            int kk = i >> 7, c = i & 127;
            Ws[kk * 128 + c] = W[(k0 + kk) * F + c];
        }
        // stage h chunk transposed: 32 rows x 32 k
        #pragma unroll
        for (int j = 0; j < 4; ++j) {
            int i = t + 256 * j;          // 0..1023
            int r = i >> 5, kk = i & 31;
            int row = min(r0 + r, N - 1);
            Hs[kk * 36 + r] = h[(long long)row * F + k0 + kk];
        }
        __syncthreads();
        #pragma unroll
        for (int kk = 0; kk < 32; ++kk) {
            float4 hv = *(const float4*)&Hs[kk * 36 + 4 * tr];
            float4 wv = *(const float4*)&Ws[kk * 128 + 4 * tc];
            a0.x = fmaf(hv.x, wv.x, a0.x); a0.y = fmaf(hv.x, wv.y, a0.y);
            a0.z = fmaf(hv.x, wv.z, a0.z); a0.w = fmaf(hv.x, wv.w, a0.w);
            a1.x = fmaf(hv.y, wv.x, a1.x); a1.y = fmaf(hv.y, wv.y, a1.y);
            a1.z = fmaf(hv.y, wv.z, a1.z); a1.w = fmaf(hv.y, wv.w, a1.w);
            a2.x = fmaf(hv.z, wv.x, a2.x); a2.y = fmaf(hv.z, wv.y, a2.y);
            a2.z = fmaf(hv.z, wv.z, a2.z); a2.w = fmaf(hv.z, wv.w, a2.w);
            a3.x = fmaf(hv.w, wv.x, a3.x); a3.y = fmaf(hv.w, wv.y, a3.y);
            a3.z = fmaf(hv.w, wv.z, a3.z); a3.w = fmaf(hv.w, wv.w, a3.w);
        }
        __syncthreads();
    }

    float4 bv = *(const float4*)&bias[4 * tc];
    float4 acc[4] = {a0, a1, a2, a3};
    #pragma unroll
    for (int i = 0; i < 4; ++i) {
        int row = r0 + 4 * tr + i;
        if (row < N) {
            float4 o = acc[i];
            o.x += bv.x; o.y += bv.y; o.z += bv.z; o.w += bv.w;
            *(float4*)&out[(long long)row * F + 4 * tc] = o;
        }
    }
}

extern "C" void kernel_launch(void* const* d_in, const int* in_sizes, int n_in,
                              void* d_out, int out_size, void* d_ws, size_t ws_size,
                              hipStream_t stream) {
    const float* x    = (const float*)d_in[0];
    const int*   src  = (const int*)d_in[1];
    const int*   dst  = (const int*)d_in[2];
    const float* W    = (const float*)d_in[3];
    const float* bias = (const float*)d_in[4];
    float* out = (float*)d_out;

    const int N = in_sizes[0] / F;     // 50000
    const int E = in_sizes[1];         // 800000

    // workspace layout (all 4-byte elems)
    int*   cnt_out = (int*)d_ws;            // [N]
    int*   cnt_in  = cnt_out + N;           // [N] -> becomes cursor
    int*   row_off = cnt_in + N;            // [N+1]
    int*   csr_src = row_off + N + 1;       // [E]
    float* inv_out = (float*)(csr_src + E); // [N]
    float* h       = inv_out + N;           // [N*F]

    // zero only the counters
    hipMemsetAsync(d_ws, 0, (size_t)2 * N * sizeof(int), stream);

    deg_kernel<<<(E + 255) / 256, 256, 0, stream>>>(src, dst, cnt_out, cnt_in, E);
    scan_kernel<<<1, 1024, 0, stream>>>(cnt_in, row_off, N);
    inv_kernel<<<(N + 255) / 256, 256, 0, stream>>>(cnt_out, inv_out, N);
    fill_kernel<<<(E + 255) / 256, 256, 0, stream>>>(src, dst, cnt_in, csr_src, E);
    gather_kernel<<<(N + 3) / 4, 256, 0, stream>>>(x, csr_src, row_off, inv_out, h, N);
    gemm_kernel<<<(N + 31) / 32, 256, 0, stream>>>(h, W, bias, out, N);
}

// Round 3
// 292.235 us; speedup vs baseline: 6.0457x; 1.4178x over previous
//
#include <hip/hip_runtime.h>

#define F 128

// ---- 1. degree counts (int atomics) ----
__global__ __launch_bounds__(256)
void deg_kernel(const int* __restrict__ src, const int* __restrict__ dst,
                int* __restrict__ cnt_out, int* __restrict__ cnt_in, int E) {
    int e = blockIdx.x * blockDim.x + threadIdx.x;
    if (e < E) {
        atomicAdd(&cnt_out[src[e]], 1);
        atomicAdd(&cnt_in[dst[e]], 1);
    }
}

// ---- 2a. per-block (1024-elem) sums ----
__global__ __launch_bounds__(256)
void scan_p1(const int* __restrict__ cnt, int* __restrict__ bsum, int N) {
    int b = blockIdx.x, t = threadIdx.x;
    int i0 = b * 1024 + t * 4;
    int s = 0;
    #pragma unroll
    for (int j = 0; j < 4; ++j) { int i = i0 + j; if (i < N) s += cnt[i]; }
    #pragma unroll
    for (int off = 32; off > 0; off >>= 1) s += __shfl_down(s, off);
    __shared__ int ws[4];
    int lane = t & 63, w = t >> 6;
    if (lane == 0) ws[w] = s;
    __syncthreads();
    if (t == 0) bsum[b] = ws[0] + ws[1] + ws[2] + ws[3];
}

// ---- 2b. exclusive scan of block sums (single wave; NB <= 64) ----
__global__ __launch_bounds__(64)
void scan_p2(const int* __restrict__ bsum, int* __restrict__ boff,
             int* __restrict__ row_off, int NB, int N, int E) {
    int t = threadIdx.x;
    int v = (t < NB) ? bsum[t] : 0;
    int incl = v;
    #pragma unroll
    for (int off = 1; off < 64; off <<= 1) {
        int u = __shfl_up(incl, off);
        if (t >= off) incl += u;
    }
    if (t < NB) boff[t] = incl - v;
    if (t == 0) row_off[N] = E;   // sum of in-degrees == E
}

// ---- 2c. block-local exclusive scan + offset; write row_off and cursor ----
__global__ __launch_bounds__(256)
void scan_p3(const int* __restrict__ cnt, const int* __restrict__ boff,
             int* __restrict__ row_off, int* __restrict__ cursor, int N) {
    int b = blockIdx.x, t = threadIdx.x;
    int i0 = b * 1024 + t * 4;
    int v[4]; int s = 0;
    #pragma unroll
    for (int j = 0; j < 4; ++j) { int i = i0 + j; v[j] = (i < N) ? cnt[i] : 0; s += v[j]; }
    int lane = t & 63, w = t >> 6;
    int incl = s;
    #pragma unroll
    for (int off = 1; off < 64; off <<= 1) {
        int u = __shfl_up(incl, off);
        if (lane >= off) incl += u;
    }
    __shared__ int wsum[4];
    if (lane == 63) wsum[w] = incl;
    __syncthreads();
    int wbase = 0;
    #pragma unroll
    for (int j = 0; j < 4; ++j) if (j < w) wbase += wsum[j];
    int run = boff[b] + wbase + (incl - s);
    #pragma unroll
    for (int j = 0; j < 4; ++j) {
        int i = i0 + j;
        if (i < N) { row_off[i] = run; cursor[i] = run; run += v[j]; }
    }
}

// ---- 3. inv_out = rsqrt(max(deg_out,1)) ----
__global__ __launch_bounds__(256)
void inv_kernel(const int* __restrict__ cnt_out, float* __restrict__ inv_out, int N) {
    int i = blockIdx.x * blockDim.x + threadIdx.x;
    if (i < N) inv_out[i] = rsqrtf(fmaxf((float)cnt_out[i], 1.0f));
}

// ---- 4. bucket edges into CSR ----
__global__ __launch_bounds__(256)
void fill_kernel(const int* __restrict__ src, const int* __restrict__ dst,
                 int* __restrict__ cursor, int* __restrict__ csr_src, int E) {
    int e = blockIdx.x * blockDim.x + threadIdx.x;
    if (e < E) {
        int pos = atomicAdd(&cursor[dst[e]], 1);
        csr_src[pos] = src[e];
    }
}

// ---- 5. gather: one wave per node, 64 lanes x float2 = 128 feats ----
__global__ __launch_bounds__(256)
void gather_kernel(const float* __restrict__ x, const int* __restrict__ csr_src,
                   const int* __restrict__ row_off, const float* __restrict__ inv_out,
                   float* __restrict__ h, int N) {
    int v = blockIdx.x * 4 + (threadIdx.x >> 6);
    if (v >= N) return;
    int lane = threadIdx.x & 63;
    int beg = row_off[v];
    int end = row_off[v + 1];
    float2 acc0 = make_float2(0.0f, 0.0f);
    float2 acc1 = make_float2(0.0f, 0.0f);
    int j = beg;
    for (; j + 1 < end; j += 2) {
        int s0 = csr_src[j];
        int s1 = csr_src[j + 1];
        float i0 = inv_out[s0];
        float i1 = inv_out[s1];
        float2 xv0 = *(const float2*)(x + (long long)s0 * F + lane * 2);
        float2 xv1 = *(const float2*)(x + (long long)s1 * F + lane * 2);
        acc0.x = fmaf(xv0.x, i0, acc0.x);
        acc0.y = fmaf(xv0.y, i0, acc0.y);
        acc1.x = fmaf(xv1.x, i1, acc1.x);
        acc1.y = fmaf(xv1.y, i1, acc1.y);
    }
    if (j < end) {
        int s0 = csr_src[j];
        float i0 = inv_out[s0];
        float2 xv0 = *(const float2*)(x + (long long)s0 * F + lane * 2);
        acc0.x = fmaf(xv0.x, i0, acc0.x);
        acc0.y = fmaf(xv0.y, i0, acc0.y);
    }
    float invd = rsqrtf(fmaxf((float)(end - beg), 1.0f));
    ((float2*)(h + (long long)v * F))[lane] =
        make_float2((acc0.x + acc1.x) * invd, (acc0.y + acc1.y) * invd);
}

// ---- 6. tiled GEMM: out = h @ W + bias. 32 rows x 128 cols per block ----
__global__ __launch_bounds__(256)
void gemm_kernel(const float* __restrict__ h, const float* __restrict__ W,
                 const float* __restrict__ bias, float* __restrict__ out, int N) {
    __shared__ float Ws[32 * 128];
    __shared__ float Hs[32 * 36];
    const int t = threadIdx.x;
    const int r0 = blockIdx.x * 32;
    const int tc = t & 31;
    const int tr = t >> 5;

    float4 a0 = {0,0,0,0}, a1 = {0,0,0,0}, a2 = {0,0,0,0}, a3 = {0,0,0,0};

    for (int kc = 0; kc < 4; ++kc) {
        const int k0 = kc * 32;
        #pragma unroll
        for (int j = 0; j < 16; ++j) {
            int i = t + 256 * j;
            int kk = i >> 7, c = i & 127;
            Ws[kk * 128 + c] = W[(k0 + kk) * F + c];
        }
        #pragma unroll
        for (int j = 0; j < 4; ++j) {
            int i = t + 256 * j;
            int r = i >> 5, kk = i & 31;
            int row = min(r0 + r, N - 1);
            Hs[kk * 36 + r] = h[(long long)row * F + k0 + kk];
        }
        __syncthreads();
        #pragma unroll
        for (int kk = 0; kk < 32; ++kk) {
            float4 hv = *(const float4*)&Hs[kk * 36 + 4 * tr];
            float4 wv = *(const float4*)&Ws[kk * 128 + 4 * tc];
            a0.x = fmaf(hv.x, wv.x, a0.x); a0.y = fmaf(hv.x, wv.y, a0.y);
            a0.z = fmaf(hv.x, wv.z, a0.z); a0.w = fmaf(hv.x, wv.w, a0.w);
            a1.x = fmaf(hv.y, wv.x, a1.x); a1.y = fmaf(hv.y, wv.y, a1.y);
            a1.z = fmaf(hv.y, wv.z, a1.z); a1.w = fmaf(hv.y, wv.w, a1.w);
            a2.x = fmaf(hv.z, wv.x, a2.x); a2.y = fmaf(hv.z, wv.y, a2.y);
            a2.z = fmaf(hv.z, wv.z, a2.z); a2.w = fmaf(hv.z, wv.w, a2.w);
            a3.x = fmaf(hv.w, wv.x, a3.x); a3.y = fmaf(hv.w, wv.y, a3.y);
            a3.z = fmaf(hv.w, wv.z, a3.z); a3.w = fmaf(hv.w, wv.w, a3.w);
        }
        __syncthreads();
    }

    float4 bv = *(const float4*)&bias[4 * tc];
    float4 acc[4] = {a0, a1, a2, a3};
    #pragma unroll
    for (int i = 0; i < 4; ++i) {
        int row = r0 + 4 * tr + i;
        if (row < N) {
            float4 o = acc[i];
            o.x += bv.x; o.y += bv.y; o.z += bv.z; o.w += bv.w;
            *(float4*)&out[(long long)row * F + 4 * tc] = o;
        }
    }
}

extern "C" void kernel_launch(void* const* d_in, const int* in_sizes, int n_in,
                              void* d_out, int out_size, void* d_ws, size_t ws_size,
                              hipStream_t stream) {
    const float* x    = (const float*)d_in[0];
    const int*   src  = (const int*)d_in[1];
    const int*   dst  = (const int*)d_in[2];
    const float* W    = (const float*)d_in[3];
    const float* bias = (const float*)d_in[4];
    float* out = (float*)d_out;

    const int N = in_sizes[0] / F;     // 50000
    const int E = in_sizes[1];         // 800000
    const int NB = (N + 1023) / 1024;  // 49 scan blocks

    // workspace layout (all 4-byte elems)
    int*   cnt_out = (int*)d_ws;            // [N]  (reused as cursor after inv)
    int*   cnt_in  = cnt_out + N;           // [N]
    int*   row_off = cnt_in + N;            // [N+1]
    int*   csr_src = row_off + N + 1;       // [E]
    float* inv_out = (float*)(csr_src + E); // [N]
    int*   bsum    = (int*)(inv_out + N);   // [NB]
    int*   boff    = bsum + NB;             // [NB]
    float* h       = (float*)(boff + NB);   // [N*F]

    // zero only the counters
    hipMemsetAsync(d_ws, 0, (size_t)2 * N * sizeof(int), stream);

    deg_kernel<<<(E + 255) / 256, 256, 0, stream>>>(src, dst, cnt_out, cnt_in, E);
    scan_p1<<<NB, 256, 0, stream>>>(cnt_in, bsum, N);
    scan_p2<<<1, 64, 0, stream>>>(bsum, boff, row_off, NB, N, E);
    inv_kernel<<<(N + 255) / 256, 256, 0, stream>>>(cnt_out, inv_out, N);
    // cursor reuses cnt_out (inv_kernel already consumed it; stream is in-order)
    int* cursor = cnt_out;
    scan_p3<<<NB, 256, 0, stream>>>(cnt_in, boff, row_off, cursor, N);
    fill_kernel<<<(E + 255) / 256, 256, 0, stream>>>(src, dst, cursor, csr_src, E);
    gather_kernel<<<(N + 3) / 4, 256, 0, stream>>>(x, csr_src, row_off, inv_out, h, N);
    gemm_kernel<<<(N + 31) / 32, 256, 0, stream>>>(h, W, bias, out, N);
}